// Round 9
// baseline (86.657 us; speedup 1.0000x reference)
//
#include <hip/hip_runtime.h>
#include <hip/hip_fp16.h>
#include <math.h>

#define B_N   2
#define A_N   180
#define HR_N  512
#define H_OUT 512
#define W_OUT 512
#define PAD   51               // int(0.1 * 512)
#define HP    614              // H_OUT + 2*PAD
#define WP    614
#define GUARD 80               // zero guard each side
#define HPP   (HP + 2*GUARD)   // 774
#define NPIX  (H_OUT * W_OUT)

#define TW     16              // tile width (pixels)
#define TH     8               // tile height -> 128 px, 256 thr (2 angle halves)
#define HALF_A 90
#define CH     30              // angles per LDS chunk (per half)
#define NCH    (HALF_A / CH)   // 3
#define WIN    20              // window entries per angle per tile (span <= 18.3)

// Workspace:
//   pk2[A_N][HPP] uint2: {half2(b0[y],b1[y]), half2(b0[y+1],b1[y+1])}, zero-guarded
//   tg[A_N] float2: {cos, sin}

__device__ __forceinline__ float col_val(const float* __restrict__ sino,
                                         int b, int a, int yy) {
    if (yy < 0 || yy >= HP) return 0.0f;
    float src = ((float)yy + 0.5f) * ((float)HR_N / (float)HP) - 0.5f;
    src = fminf(fmaxf(src, 0.0f), (float)(HR_N - 1));
    int i0 = (int)floorf(src);
    int i1 = min(i0 + 1, HR_N - 1);
    float wH = src - (float)i0;
    const float* srow = sino + ((size_t)b * A_N + a) * HR_N;
    return srow[i0] * (1.0f - wH) + srow[i1] * wH;
}

__global__ void prep_kernel(const float* __restrict__ sino,
                            const float* __restrict__ angles,
                            uint2* __restrict__ pk2,
                            float2* __restrict__ tg) {
    int idx = blockIdx.x * blockDim.x + threadIdx.x;
    if (idx < A_N) {
        float th = -angles[idx] * (float)(M_PI / 180.0);
        tg[idx] = make_float2(cosf(th), sinf(th));
    }
    const int total = A_N * HPP;
    if (idx < total) {
        int y = idx % HPP;
        int a = idx / HPP;
        int yy = y - GUARD;
        float v00 = col_val(sino, 0, a, yy);
        float v10 = col_val(sino, 1, a, yy);
        float v01 = col_val(sino, 0, a, yy + 1);
        float v11 = col_val(sino, 1, a, yy + 1);
        __half2 lo = __floats2half2_rn(v00, v10);
        __half2 hi = __floats2half2_rn(v01, v11);
        uint2 u;
        u.x = *(unsigned int*)&lo;
        u.y = *(unsigned int*)&hi;
        pk2[idx] = u;
    }
}

__global__ __launch_bounds__(256, 8) void bp_kernel(const uint2* __restrict__ pk2,
                                                    const float2* __restrict__ tgv,
                                                    float* __restrict__ out) {
    __shared__ int   s_base[A_N];
    __shared__ uint2 s_win[2 * CH * WIN]; // [half][la][j]
    __shared__ float s_red[2][128];

    int t  = threadIdx.x;
    int tx = blockIdx.x, ty = blockIdx.y;
    float Xc = (float)(tx * TW) - 248.0f;   // tile-center X (= +7.5 - 255.5)
    float Yc = (float)(ty * TH) - 252.0f;   // tile-center Y (= +3.5 - 255.5)

    if (t < A_N) {
        float2 cs = tgv[t];
        float iyc = fmaf(cs.y, Xc, fmaf(cs.x, Yc, 306.5f));
        s_base[t] = (int)floorf(iyc) - 9;   // window covers [base, base+19]
    }

    int half = t >> 7;                      // waves 0-1: angles 0-89; waves 2-3: 90-179
    int tt   = t & 127;
    int lx = tt & (TW - 1), ly = tt >> 4;
    float X = (float)(tx * TW + lx) - 255.5f;
    float Y = (float)(ty * TH + ly) - 255.5f;

    float acc0 = 0.0f, acc1 = 0.0f;
    __syncthreads();

    // Interior tiles: ix in [0,613] for every pixel & angle -> xfac == 1
    bool interior = (Xc * Xc + Yc * Yc) <= 87500.0f;

    for (int ch = 0; ch < NCH; ++ch) {
        // Stage CH angle-windows for BOTH halves into LDS
        for (int e = t; e < 2 * CH * WIN; e += 256) {
            int hh = e / (CH * WIN);
            int r  = e - hh * (CH * WIN);
            int la = r / WIN;
            int j  = r - la * WIN;
            int a  = hh * HALF_A + ch * CH + la;
            s_win[e] = pk2[(size_t)a * HPP + (GUARD + s_base[a] + j)];
        }
        __syncthreads();

        const int aoff = half * HALF_A + ch * CH;  // wave-uniform
        const int woff = half * (CH * WIN);
        if (interior) {
            __half2 hacc = __float2half2_rn(0.0f);
#pragma unroll
            for (int la = 0; la < CH; ++la) {
                float2 cs = tgv[aoff + la];        // wave-uniform -> s_load_dwordx2
                float c = cs.x, s = cs.y;
                float iyc = fmaf(s, Xc, fmaf(c, Yc, 306.5f));
                float Kf  = 315.5f - floorf(iyc);  // exact: 306.5 - base
                float f   = fmaf(s, X, fmaf(c, Y, Kf));   // in (0.7, 18.3)
                int   li  = (int)f;
                float wy  = f - (float)li;
                uint2 cv  = s_win[woff + la * WIN + li];  // ds_read_b64
                __half2 lo = *(__half2*)&cv.x;
                __half2 hi = *(__half2*)&cv.y;
                __half2 r2 = __hfma2(__float2half2_rn(wy), __hsub2(hi, lo), lo);
                hacc = __hadd2(hacc, r2);
            }
            acc0 += __low2float(hacc);
            acc1 += __high2float(hacc);
        } else {
#pragma unroll
            for (int la = 0; la < CH; ++la) {
                float2 cs = tgv[aoff + la];
                float c = cs.x, s = cs.y;
                float iyc = fmaf(s, Xc, fmaf(c, Yc, 306.5f));
                float Kf  = 315.5f - floorf(iyc);
                float f   = fmaf(s, X, fmaf(c, Y, Kf));
                int   li  = (int)f;
                float wy  = f - (float)li;
                uint2 cv  = s_win[woff + la * WIN + li];
                __half2 lo = *(__half2*)&cv.x;
                __half2 hi = *(__half2*)&cv.y;
                __half2 r2 = __hfma2(__float2half2_rn(wy), __hsub2(hi, lo), lo);
                float ix = fmaf(c, X, fmaf(-s, Y, 306.5f));
                float xf = fminf(fmaxf(ix + 1.0f, 0.0f), 1.0f)
                         * fminf(fmaxf((float)WP - ix, 0.0f), 1.0f);
                acc0 = fmaf(xf, __low2float(r2), acc0);
                acc1 = fmaf(xf, __high2float(r2), acc1);
            }
        }
        __syncthreads();
    }

    // Combine the two angle halves (no atomics, no global memset)
    if (half) {
        s_red[0][tt] = acc0;
        s_red[1][tt] = acc1;
    }
    __syncthreads();
    if (!half) {
        const float inv = 1.0f / (180.0f + 1e-6f);
        float a0 = (acc0 + s_red[0][tt]) * inv;
        float a1 = (acc1 + s_red[1][tt]) * inv;
        int idx = (ty * TH + ly) * W_OUT + (tx * TW + lx);
        out[idx]        = a0;
        out[NPIX + idx] = a1;
    }
}

extern "C" void kernel_launch(void* const* d_in, const int* in_sizes, int n_in,
                              void* d_out, int out_size, void* d_ws, size_t ws_size,
                              hipStream_t stream) {
    const float* sino   = (const float*)d_in[0];
    const float* angles = (const float*)d_in[1];
    char*   ws  = (char*)d_ws;
    uint2*  pk2 = (uint2*)ws;                              // A_N * HPP * 8 B
    float2* tg  = (float2*)(ws + (size_t)A_N * HPP * sizeof(uint2));

    const int total = A_N * HPP;
    prep_kernel<<<(total + 255) / 256, 256, 0, stream>>>(sino, angles, pk2, tg);

    dim3 grid(W_OUT / TW, H_OUT / TH);                     // 32 x 64 = 2048 blocks
    bp_kernel<<<grid, 256, 0, stream>>>(pk2, tg, (float*)d_out);
}

// Round 10
// 84.092 us; speedup vs baseline: 1.0305x; 1.0305x over previous
//
#include <hip/hip_runtime.h>
#include <hip/hip_fp16.h>
#include <math.h>

#define B_N   2
#define A_N   180
#define HR_N  512
#define H_OUT 512
#define W_OUT 512
#define PAD   51               // int(0.1 * 512)
#define HP    614              // H_OUT + 2*PAD
#define WP    614
#define GUARD 80               // zero guard each side
#define HPP   (HP + 2*GUARD)   // 774
#define NPIX  (H_OUT * W_OUT)

#define TW    16               // tile width (pixels)
#define TH    8                // tile height -> 128 px; 256 thr = 4 angle-quarters x 64
#define QA    45               // angles per quarter
#define CH_Q  15               // angles per quarter per LDS chunk
#define NCH   3                // chunks (QA / CH_Q)
#define WIN   20               // window entries per angle per tile (span <= 18.6)

// Workspace:
//   pk2[A_N][HPP] uint2: {half2(b0[y],b1[y]), half2(b0[y+1],b1[y+1])}, zero-guarded
//   tg[A_N] float2: {cos, sin}

__device__ __forceinline__ float col_val(const float* __restrict__ sino,
                                         int b, int a, int yy) {
    if (yy < 0 || yy >= HP) return 0.0f;
    float src = ((float)yy + 0.5f) * ((float)HR_N / (float)HP) - 0.5f;
    src = fminf(fmaxf(src, 0.0f), (float)(HR_N - 1));
    int i0 = (int)floorf(src);
    int i1 = min(i0 + 1, HR_N - 1);
    float wH = src - (float)i0;
    const float* srow = sino + ((size_t)b * A_N + a) * HR_N;
    return srow[i0] * (1.0f - wH) + srow[i1] * wH;
}

__global__ void prep_kernel(const float* __restrict__ sino,
                            const float* __restrict__ angles,
                            uint2* __restrict__ pk2,
                            float2* __restrict__ tg) {
    int idx = blockIdx.x * blockDim.x + threadIdx.x;
    if (idx < A_N) {
        float th = -angles[idx] * (float)(M_PI / 180.0);
        tg[idx] = make_float2(cosf(th), sinf(th));
    }
    const int total = A_N * HPP;
    if (idx < total) {
        int y = idx % HPP;
        int a = idx / HPP;
        int yy = y - GUARD;
        float v00 = col_val(sino, 0, a, yy);
        float v10 = col_val(sino, 1, a, yy);
        float v01 = col_val(sino, 0, a, yy + 1);
        float v11 = col_val(sino, 1, a, yy + 1);
        __half2 lo = __floats2half2_rn(v00, v10);
        __half2 hi = __floats2half2_rn(v01, v11);
        uint2 u;
        u.x = *(unsigned int*)&lo;
        u.y = *(unsigned int*)&hi;
        pk2[idx] = u;
    }
}

template <bool INTERIOR>
__device__ __forceinline__ void bp_body(const uint2* __restrict__ pk2,
                                        const float2* __restrict__ s_tg,
                                        const int* __restrict__ s_base,
                                        uint2* __restrict__ s_win,
                                        int t, int q, float X, float Y,
                                        float Xc, float Yc,
                                        float& a00, float& a01, float& a10, float& a11) {
    for (int ch = 0; ch < NCH; ++ch) {
        // Stage CH_Q angle-windows for ALL 4 quarters into LDS (1200 uint2)
        for (int e = t; e < 4 * CH_Q * WIN; e += 256) {
            int wid = e / WIN;
            int j   = e - wid * WIN;
            int qq  = wid / CH_Q;
            int la  = wid - qq * CH_Q;
            int a   = qq * QA + ch * CH_Q + la;
            s_win[e] = pk2[(size_t)a * HPP + (GUARD + s_base[a] + j)];
        }
        __syncthreads();

        const int abase = q * QA + ch * CH_Q;     // wave-uniform
        const int wbase = q * (CH_Q * WIN);
        if (INTERIOR) {
            __half2 h0 = __float2half2_rn(0.0f);
            __half2 h1 = __float2half2_rn(0.0f);
#pragma unroll
            for (int la = 0; la < CH_Q; ++la) {
                float2 cs = s_tg[abase + la];       // broadcast ds_read_b64
                float c = cs.x, s = cs.y;
                float iyc = fmaf(s, Xc, fmaf(c, Yc, 306.5f));
                float Kf  = 315.5f - floorf(iyc);   // exact: 306.5 - base
                float f0  = fmaf(s, X, fmaf(c, Y, Kf));    // in (0.7, 18.3)
                float f1  = f0 + s;
                int   li0 = (int)f0;  float wy0 = f0 - (float)li0;
                int   li1 = (int)f1;  float wy1 = f1 - (float)li1;
                uint2 cv0 = s_win[wbase + la * WIN + li0]; // ds_read_b64
                uint2 cv1 = s_win[wbase + la * WIN + li1];
                __half2 lo0 = *(__half2*)&cv0.x, hi0 = *(__half2*)&cv0.y;
                __half2 lo1 = *(__half2*)&cv1.x, hi1 = *(__half2*)&cv1.y;
                h0 = __hadd2(h0, __hfma2(__float2half2_rn(wy0), __hsub2(hi0, lo0), lo0));
                h1 = __hadd2(h1, __hfma2(__float2half2_rn(wy1), __hsub2(hi1, lo1), lo1));
            }
            a00 += __low2float(h0);  a01 += __high2float(h0);
            a10 += __low2float(h1);  a11 += __high2float(h1);
        } else {
#pragma unroll
            for (int la = 0; la < CH_Q; ++la) {
                float2 cs = s_tg[abase + la];
                float c = cs.x, s = cs.y;
                float iyc = fmaf(s, Xc, fmaf(c, Yc, 306.5f));
                float Kf  = 315.5f - floorf(iyc);
                float f0  = fmaf(s, X, fmaf(c, Y, Kf));
                float f1  = f0 + s;
                int   li0 = (int)f0;  float wy0 = f0 - (float)li0;
                int   li1 = (int)f1;  float wy1 = f1 - (float)li1;
                uint2 cv0 = s_win[wbase + la * WIN + li0];
                uint2 cv1 = s_win[wbase + la * WIN + li1];
                __half2 lo0 = *(__half2*)&cv0.x, hi0 = *(__half2*)&cv0.y;
                __half2 lo1 = *(__half2*)&cv1.x, hi1 = *(__half2*)&cv1.y;
                __half2 r0 = __hfma2(__float2half2_rn(wy0), __hsub2(hi0, lo0), lo0);
                __half2 r1 = __hfma2(__float2half2_rn(wy1), __hsub2(hi1, lo1), lo1);
                float ix0 = fmaf(c, X, fmaf(-s, Y, 306.5f));
                float ix1 = ix0 + c;
                float xf0 = fminf(fmaxf(ix0 + 1.0f, 0.0f), 1.0f)
                          * fminf(fmaxf((float)WP - ix0, 0.0f), 1.0f);
                float xf1 = fminf(fmaxf(ix1 + 1.0f, 0.0f), 1.0f)
                          * fminf(fmaxf((float)WP - ix1, 0.0f), 1.0f);
                a00 = fmaf(xf0, __low2float(r0),  a00);
                a01 = fmaf(xf0, __high2float(r0), a01);
                a10 = fmaf(xf1, __low2float(r1),  a10);
                a11 = fmaf(xf1, __high2float(r1), a11);
            }
        }
        __syncthreads();
    }
}

__global__ __launch_bounds__(256, 8) void bp_kernel(const uint2* __restrict__ pk2,
                                                    const float2* __restrict__ tgv,
                                                    float* __restrict__ out) {
    __shared__ float2 s_tg[A_N];
    __shared__ int    s_base[A_N];
    __shared__ uint2  s_win[4 * CH_Q * WIN];   // 1200 entries, 9.6 KB
    __shared__ float  s_red[3][256];           // [quarter-1][batch*128 + pix]

    int t  = threadIdx.x;
    int tx = blockIdx.x, ty = blockIdx.y;
    float Xc = (float)(tx * TW) - 248.0f;      // tile-center X (= +7.5 - 255.5)
    float Yc = (float)(ty * TH) - 252.0f;      // tile-center Y (= +3.5 - 255.5)

    if (t < A_N) {
        float2 cs = tgv[t];
        s_tg[t] = cs;
        float iyc = fmaf(cs.y, Xc, fmaf(cs.x, Yc, 306.5f));
        s_base[t] = (int)floorf(iyc) - 9;      // window covers [base, base+19]
    }

    int q  = t >> 6;                           // quarter = wave id (angles q*45..q*45+44)
    int tt = t & 63;
    int lx = (tt & 7) << 1;                    // 0,2,...,14 (2 px per thread in x)
    int ly = tt >> 3;                          // 0..7
    float X = (float)(tx * TW + lx) - 255.5f;
    float Y = (float)(ty * TH + ly) - 255.5f;

    float a00 = 0.0f, a01 = 0.0f, a10 = 0.0f, a11 = 0.0f;
    __syncthreads();

    // Interior tiles: ix in [0,613] for every pixel & angle -> xfac == 1
    bool interior = (Xc * Xc + Yc * Yc) <= 87500.0f;
    if (interior)
        bp_body<true >(pk2, s_tg, s_base, s_win, t, q, X, Y, Xc, Yc, a00, a01, a10, a11);
    else
        bp_body<false>(pk2, s_tg, s_base, s_win, t, q, X, Y, Xc, Yc, a00, a01, a10, a11);

    // 4-quarter reduction in LDS (no atomics, no global memset)
    int pix = ly * TW + lx;                    // 0..126 even
    if (q != 0) {
        s_red[q - 1][pix]           = a00;
        s_red[q - 1][pix + 1]       = a10;
        s_red[q - 1][128 + pix]     = a01;
        s_red[q - 1][128 + pix + 1] = a11;
    }
    __syncthreads();
    if (q == 0) {
        const float inv = 1.0f / (180.0f + 1e-6f);
        float r00 = (a00 + s_red[0][pix]       + s_red[1][pix]       + s_red[2][pix])       * inv;
        float r10 = (a10 + s_red[0][pix+1]     + s_red[1][pix+1]     + s_red[2][pix+1])     * inv;
        float r01 = (a01 + s_red[0][128+pix]   + s_red[1][128+pix]   + s_red[2][128+pix])   * inv;
        float r11 = (a11 + s_red[0][128+pix+1] + s_red[1][128+pix+1] + s_red[2][128+pix+1]) * inv;
        int idx = (ty * TH + ly) * W_OUT + (tx * TW + lx);
        out[idx]            = r00;
        out[idx + 1]        = r10;
        out[NPIX + idx]     = r01;
        out[NPIX + idx + 1] = r11;
    }
}

extern "C" void kernel_launch(void* const* d_in, const int* in_sizes, int n_in,
                              void* d_out, int out_size, void* d_ws, size_t ws_size,
                              hipStream_t stream) {
    const float* sino   = (const float*)d_in[0];
    const float* angles = (const float*)d_in[1];
    char*   ws  = (char*)d_ws;
    uint2*  pk2 = (uint2*)ws;                              // A_N * HPP * 8 B
    float2* tg  = (float2*)(ws + (size_t)A_N * HPP * sizeof(uint2));

    const int total = A_N * HPP;
    prep_kernel<<<(total + 255) / 256, 256, 0, stream>>>(sino, angles, pk2, tg);

    dim3 grid(W_OUT / TW, H_OUT / TH);                     // 32 x 64 = 2048 blocks
    bp_kernel<<<grid, 256, 0, stream>>>(pk2, tg, (float*)d_out);
}